// Round 4
// baseline (147.165 us; speedup 1.0000x reference)
//
#include <hip/hip_runtime.h>

// B=16, N=1024, D=512, DIRECTIONS=2
#define NB 16
#define NN 1024
#define ND 512

typedef __attribute__((ext_vector_type(8))) short short8;   // 8 x bf16
typedef __attribute__((ext_vector_type(4))) float f32x4;

typedef const __attribute__((address_space(1))) void* gptr1;
typedef __attribute__((address_space(3))) void* lptr3;

#define VMCNT0() asm volatile("s_waitcnt vmcnt(0)" ::: "memory")
#define LGKM0()  asm volatile("s_waitcnt lgkmcnt(0)" ::: "memory")
#define BAR()    __builtin_amdgcn_s_barrier()

union U8 { uint4 u; short8 s; };

static __device__ __forceinline__ unsigned f2bf(float f) {
  union { float f; unsigned u; } v; v.f = f;
  unsigned r = v.u + 0x7FFFu + ((v.u >> 16) & 1u);   // RNE
  return r >> 16;
}
static __device__ __forceinline__ float bf2f(unsigned short h) {
  union { unsigned u; float f; } v; v.u = ((unsigned)h) << 16;
  return v.f;
}

// ---------------- k_wt: W [1024][512] f32 -> WT [512][1024] bf16 -------------
__global__ void k_wt(const float* __restrict__ W, unsigned short* __restrict__ WT) {
  __shared__ float t[64][65];
  int r0 = blockIdx.x * 64;
  int c0 = blockIdx.y * 64;
  int tid = threadIdx.x;
#pragma unroll
  for (int i = 0; i < 4; ++i) {
    int f = i * 256 + tid;
    int r = f >> 4, cq = f & 15;
    float4 v = *(const float4*)(W + (size_t)(r0 + r) * ND + c0 + cq * 4);
    t[r][cq * 4 + 0] = v.x; t[r][cq * 4 + 1] = v.y;
    t[r][cq * 4 + 2] = v.z; t[r][cq * 4 + 3] = v.w;
  }
  __syncthreads();
#pragma unroll
  for (int i = 0; i < 8; ++i) {
    int f = i * 256 + tid;
    int oc = f >> 5;
    int on = (f & 31) * 2;
    unsigned lo = f2bf(t[on][oc]), hi = f2bf(t[on + 1][oc]);
    *(unsigned*)(WT + (size_t)(c0 + oc) * NN + r0 + on) = lo | (hi << 16);
  }
}

// -------- k_pack: adj int32 -> 2-bit codes (bit0: ==1, bit1: ==2) + counts ---
__global__ void k_pack(const int* __restrict__ adj, unsigned* __restrict__ packed,
                       float* __restrict__ invc) {
  int wid = threadIdx.x >> 6, lane = threadIdx.x & 63;
  int wrow0 = (blockIdx.x * 4 + wid) * 4;
#pragma unroll
  for (int r = 0; r < 4; ++r) {
    int row = wrow0 + r;
    const int* p = adj + (size_t)row * NN + lane * 16;
    unsigned u = 0;
#pragma unroll
    for (int i = 0; i < 4; ++i) {
      int4 v = *(const int4*)(p + i * 4);
      u |= ((unsigned)v.x << (8 * i)) | ((unsigned)v.y << (8 * i + 2))
         | ((unsigned)v.z << (8 * i + 4)) | ((unsigned)v.w << (8 * i + 6));
    }
    packed[(size_t)row * 64 + lane] = u;
    unsigned c1 = __popc(u & 0x55555555u);
    unsigned c2 = __popc(u & 0xAAAAAAAAu);
    unsigned pr = c1 | (c2 << 16);
#pragma unroll
    for (int o = 32; o; o >>= 1) pr += __shfl_xor(pr, o);
    if (lane == 0) {
      invc[row * 2 + 0] = 1.0f / ((float)(pr & 0xFFFFu) + 1e-13f);
      invc[row * 2 + 1] = 1.0f / ((float)(pr >> 16) + 1e-13f);
    }
  }
}

// -------- k_pre: Pt_j[b][d][m] = bf16( sum_c W[j*512+c][d] * hid[b][m][c] ) --
__global__ __launch_bounds__(256, 2) void k_pre(
    const float* __restrict__ hid, const unsigned short* __restrict__ WT,
    unsigned short* __restrict__ Pt1, unsigned short* __restrict__ Pt2) {
  __shared__ __align__(16) char smem[49152];
  char* A1 = smem;
  char* A2 = smem + 16384;
  char* Bh = smem + 32768;

  int phys = blockIdx.x;
  int logical = (phys & 7) * 64 + (phys >> 3);
  int b = logical >> 5;
  int rem = logical & 31;
  int dt = rem >> 3, mt = rem & 7;
  int d0 = dt * 128, m0 = mt * 128;

  int tid = threadIdx.x, lane = tid & 63, wid = tid >> 6;
  int wr = wid >> 1, wc = wid & 1;

  const float* hb = hid + (size_t)b * NN * ND;

  f32x4 acc1[4][4], acc2[4][4];
  f32x4 zero = {0.f, 0.f, 0.f, 0.f};
#pragma unroll
  for (int i = 0; i < 4; ++i)
#pragma unroll
    for (int j = 0; j < 4; ++j) { acc1[i][j] = zero; acc2[i][j] = zero; }

  float4 fc[8], fn[8];
#pragma unroll
  for (int it = 0; it < 8; ++it) {
    int f = it * 256 + tid;
    fc[it] = *(const float4*)(hb + (size_t)(m0 + (f >> 4)) * ND + (f & 15) * 4);
  }
#pragma unroll
  for (int i = 0; i < 4; ++i) {
    int q = wid * 4 + i;
    int r = q * 8 + (lane >> 3);
    int sl = (lane & 7) ^ (r & 7);
    __builtin_amdgcn_global_load_lds((gptr1)(WT + (size_t)(d0 + r) * NN + sl * 8),
                                     (lptr3)(A1 + q * 1024), 16, 0, 0);
    __builtin_amdgcn_global_load_lds((gptr1)(WT + (size_t)(d0 + r) * NN + 512 + sl * 8),
                                     (lptr3)(A2 + q * 1024), 16, 0, 0);
  }

  for (int kt = 0; kt < 8; ++kt) {
    int k0 = kt * 64;
#pragma unroll
    for (int it = 0; it < 8; ++it) {
      int f = it * 256 + tid;
      int row = f >> 4, colq = f & 15;
      float4 v = fc[it];
      unsigned lo = f2bf(v.x) | (f2bf(v.y) << 16);
      unsigned hi = f2bf(v.z) | (f2bf(v.w) << 16);
      int addr = row * 128 + (((colq >> 1) ^ (row & 7)) * 16) + (colq & 1) * 8;
      *(uint2*)(Bh + addr) = make_uint2(lo, hi);
    }
    VMCNT0();
    if (kt < 7) {
#pragma unroll
      for (int it = 0; it < 8; ++it) {
        int f = it * 256 + tid;
        fn[it] = *(const float4*)(hb + (size_t)(m0 + (f >> 4)) * ND + k0 + 64 + (f & 15) * 4);
      }
    }
    LGKM0();
    BAR();
#pragma unroll
    for (int ks = 0; ks < 2; ++ks) {
      short8 a1[4], a2[4], bf[4];
#pragma unroll
      for (int mi = 0; mi < 4; ++mi) {
        int row = wr * 64 + mi * 16 + (lane & 15);
        int slot = (ks * 4 + (lane >> 4)) ^ (row & 7);
        a1[mi] = *(const short8*)(A1 + row * 128 + slot * 16);
        a2[mi] = *(const short8*)(A2 + row * 128 + slot * 16);
      }
#pragma unroll
      for (int nj = 0; nj < 4; ++nj) {
        int col = wc * 64 + nj * 16 + (lane & 15);
        int slot = (ks * 4 + (lane >> 4)) ^ (col & 7);
        bf[nj] = *(const short8*)(Bh + col * 128 + slot * 16);
      }
#pragma unroll
      for (int mi = 0; mi < 4; ++mi)
#pragma unroll
        for (int nj = 0; nj < 4; ++nj) {
          acc1[mi][nj] = __builtin_amdgcn_mfma_f32_16x16x32_bf16(a1[mi], bf[nj], acc1[mi][nj], 0, 0, 0);
          acc2[mi][nj] = __builtin_amdgcn_mfma_f32_16x16x32_bf16(a2[mi], bf[nj], acc2[mi][nj], 0, 0, 0);
        }
    }
    BAR();
    if (kt < 7) {
#pragma unroll
      for (int i = 0; i < 4; ++i) {
        int q = wid * 4 + i;
        int r = q * 8 + (lane >> 3);
        int sl = (lane & 7) ^ (r & 7);
        __builtin_amdgcn_global_load_lds((gptr1)(WT + (size_t)(d0 + r) * NN + k0 + 64 + sl * 8),
                                         (lptr3)(A1 + q * 1024), 16, 0, 0);
        __builtin_amdgcn_global_load_lds((gptr1)(WT + (size_t)(d0 + r) * NN + 512 + k0 + 64 + sl * 8),
                                         (lptr3)(A2 + q * 1024), 16, 0, 0);
      }
#pragma unroll
      for (int it = 0; it < 8; ++it) fc[it] = fn[it];
    }
    __builtin_amdgcn_sched_barrier(0);
  }
  unsigned short* P1b = Pt1 + (size_t)b * ND * NN;
  unsigned short* P2b = Pt2 + (size_t)b * ND * NN;
#pragma unroll
  for (int mi = 0; mi < 4; ++mi) {
#pragma unroll
    for (int rr = 0; rr < 4; ++rr) {
      int rowd = d0 + wr * 64 + mi * 16 + (lane >> 4) * 4 + rr;
#pragma unroll
      for (int nj = 0; nj < 4; ++nj) {
        int colm = m0 + wc * 64 + nj * 16 + (lane & 15);
        P1b[(size_t)rowd * NN + colm] = (unsigned short)f2bf(acc1[mi][nj][rr]);
        P2b[(size_t)rowd * NN + colm] = (unsigned short)f2bf(acc2[mi][nj][rr]);
      }
    }
  }
}

// -------- k_main: preS[n][d] = bf16(relu(i1*(M1@Pt1) + i2*(M2@Pt2) + bias) + hid)
// LDS-free, barrier-free: A-frags unpacked per-lane from 2-bit codes in regs;
// B-frags loaded direct from global (L1/L2), reloaded-after-use one kt ahead.
__global__ __launch_bounds__(256, 2) void k_main(
    const unsigned* __restrict__ packed, const unsigned short* __restrict__ Pt1,
    const unsigned short* __restrict__ Pt2, const float* __restrict__ invc,
    const float* __restrict__ bias, const float* __restrict__ hid,
    unsigned short* __restrict__ preS) {
  int phys = blockIdx.x;
  int logical = (phys & 7) * 64 + (phys >> 3);
  int b = logical >> 5;
  int rem = logical & 31;
  int mt = rem >> 2, nt = rem & 3;
  int n0 = mt * 128, d0 = nt * 128;

  int tid = threadIdx.x, lane = tid & 63, wid = tid >> 6;
  int wr = wid >> 1, wc = wid & 1;
  int l15 = lane & 15, lq = lane >> 4;
  unsigned sh = (lq & 1) << 4;

  // code pointers: per mi, lane reads word (lq>>1) of the 4-word kt group
  const unsigned* cp[4];
#pragma unroll
  for (int mi = 0; mi < 4; ++mi)
    cp[mi] = packed + ((size_t)b * NN + n0 + wr * 64 + mi * 16 + l15) * 64 + (lq >> 1);

  // B fragment bases: lane's 16B = Pt[d_col][m..m+8], d_col = d0+wc*64+nj*16+l15
  const unsigned short* bp1 = Pt1 + ((size_t)b * ND + d0 + wc * 64 + l15) * NN + lq * 8;
  const unsigned short* bp2 = Pt2 + ((size_t)b * ND + d0 + wc * 64 + l15) * NN + lq * 8;

  f32x4 acc1[4][4], acc2[4][4];
  f32x4 zero = {0.f, 0.f, 0.f, 0.f};
#pragma unroll
  for (int i = 0; i < 4; ++i)
#pragma unroll
    for (int j = 0; j < 4; ++j) { acc1[i][j] = zero; acc2[i][j] = zero; }

  unsigned creg[4][2];
  short8 breg[2][2][4];
#pragma unroll
  for (int mi = 0; mi < 4; ++mi) {
    creg[mi][0] = cp[mi][0];
    creg[mi][1] = cp[mi][2];
  }
#pragma unroll
  for (int ks = 0; ks < 2; ++ks)
#pragma unroll
    for (int nj = 0; nj < 4; ++nj) {
      breg[0][ks][nj] = *(const short8*)(bp1 + nj * 16 * NN + ks * 32);
      breg[1][ks][nj] = *(const short8*)(bp2 + nj * 16 * NN + ks * 32);
    }

#pragma unroll 1
  for (int kt = 0; kt < 16; ++kt) {
    U8 a1[4], a2[4];
    // ---- ks = 0: unpack + MFMAs, reload breg[*][0][*] for kt+1
#pragma unroll
    for (int mi = 0; mi < 4; ++mi) {
      unsigned h = creg[mi][0] >> sh;
#pragma unroll
      for (int j = 0; j < 4; ++j) {
        unsigned t1 = (h >> (4 * j)) & 5u;
        a1[mi].u[j] = ((t1 | (t1 << 14)) & 0x00010001u) * 0x3F80u;
        unsigned t2 = (h >> (4 * j + 1)) & 5u;
        a2[mi].u[j] = ((t2 | (t2 << 14)) & 0x00010001u) * 0x3F80u;
      }
    }
#pragma unroll
    for (int nj = 0; nj < 4; ++nj) {
#pragma unroll
      for (int mi = 0; mi < 4; ++mi)
        acc1[mi][nj] = __builtin_amdgcn_mfma_f32_16x16x32_bf16(a1[mi].s, breg[0][0][nj], acc1[mi][nj], 0, 0, 0);
#pragma unroll
      for (int mi = 0; mi < 4; ++mi)
        acc2[mi][nj] = __builtin_amdgcn_mfma_f32_16x16x32_bf16(a2[mi].s, breg[1][0][nj], acc2[mi][nj], 0, 0, 0);
      breg[0][0][nj] = *(const short8*)(bp1 + nj * 16 * NN + 64);
      breg[1][0][nj] = *(const short8*)(bp2 + nj * 16 * NN + 64);
    }
    // ---- ks = 1: unpack, reload codes for kt+1, MFMAs, reload breg[*][1][*]
#pragma unroll
    for (int mi = 0; mi < 4; ++mi) {
      unsigned h = creg[mi][1] >> sh;
#pragma unroll
      for (int j = 0; j < 4; ++j) {
        unsigned t1 = (h >> (4 * j)) & 5u;
        a1[mi].u[j] = ((t1 | (t1 << 14)) & 0x00010001u) * 0x3F80u;
        unsigned t2 = (h >> (4 * j + 1)) & 5u;
        a2[mi].u[j] = ((t2 | (t2 << 14)) & 0x00010001u) * 0x3F80u;
      }
    }
#pragma unroll
    for (int mi = 0; mi < 4; ++mi) {
      creg[mi][0] = cp[mi][4];
      creg[mi][1] = cp[mi][6];
    }
#pragma unroll
    for (int nj = 0; nj < 4; ++nj) {
#pragma unroll
      for (int mi = 0; mi < 4; ++mi)
        acc1[mi][nj] = __builtin_amdgcn_mfma_f32_16x16x32_bf16(a1[mi].s, breg[0][1][nj], acc1[mi][nj], 0, 0, 0);
#pragma unroll
      for (int mi = 0; mi < 4; ++mi)
        acc2[mi][nj] = __builtin_amdgcn_mfma_f32_16x16x32_bf16(a2[mi].s, breg[1][1][nj], acc2[mi][nj], 0, 0, 0);
      breg[0][1][nj] = *(const short8*)(bp1 + nj * 16 * NN + 32 + 64);
      breg[1][1][nj] = *(const short8*)(bp2 + nj * 16 * NN + 32 + 64);
    }
#pragma unroll
    for (int mi = 0; mi < 4; ++mi) cp[mi] += 4;
    bp1 += 64; bp2 += 64;
  }

  // ---- epilogue: combine dirs, bias, relu, residual; write pre-LN bf16
#pragma unroll
  for (int mi = 0; mi < 4; ++mi) {
#pragma unroll
    for (int rr = 0; rr < 4; ++rr) {
      int n = n0 + wr * 64 + mi * 16 + lq * 4 + rr;
      float i1 = invc[((size_t)b * NN + n) * 2 + 0];
      float i2 = invc[((size_t)b * NN + n) * 2 + 1];
      const float* hrow = hid + ((size_t)b * NN + n) * ND;
      unsigned short* prow = preS + ((size_t)b * NN + n) * ND;
#pragma unroll
      for (int nj = 0; nj < 4; ++nj) {
        int d = d0 + wc * 64 + nj * 16 + l15;
        float v = acc1[mi][nj][rr] * i1 + acc2[mi][nj][rr] * i2 + bias[d];
        v = fmaxf(v, 0.f);
        v += hrow[d];
        prow[d] = (unsigned short)f2bf(v);
      }
    }
  }
}

// ---------------- k_ln: rowwise LayerNorm, bf16 preS -> f32 out --------------
__global__ void k_ln(const unsigned short* __restrict__ preS, float* __restrict__ out,
                     const float* __restrict__ gamma, const float* __restrict__ beta) {
  int row = blockIdx.x * 4 + (threadIdx.x >> 6);
  int lane = threadIdx.x & 63;
  short8 raw = *(const short8*)(preS + (size_t)row * ND + lane * 8);
  float x[8];
#pragma unroll
  for (int i = 0; i < 8; ++i) x[i] = bf2f((unsigned short)raw[i]);
  float s = 0.f;
#pragma unroll
  for (int i = 0; i < 8; ++i) s += x[i];
#pragma unroll
  for (int o = 32; o; o >>= 1) s += __shfl_xor(s, o);
  float mu = s * (1.0f / 512.0f);
  float v = 0.f;
#pragma unroll
  for (int i = 0; i < 8; ++i) { float d = x[i] - mu; v += d * d; }
#pragma unroll
  for (int o = 32; o; o >>= 1) v += __shfl_xor(v, o);
  float rs = rsqrtf(v * (1.0f / 512.0f) + 1e-5f);
  float4 g0 = *(const float4*)(gamma + lane * 8);
  float4 g1 = *(const float4*)(gamma + lane * 8 + 4);
  float4 b0 = *(const float4*)(beta + lane * 8);
  float4 b1 = *(const float4*)(beta + lane * 8 + 4);
  float4 y0, y1;
  y0.x = (x[0] - mu) * rs * g0.x + b0.x; y0.y = (x[1] - mu) * rs * g0.y + b0.y;
  y0.z = (x[2] - mu) * rs * g0.z + b0.z; y0.w = (x[3] - mu) * rs * g0.w + b0.w;
  y1.x = (x[4] - mu) * rs * g1.x + b1.x; y1.y = (x[5] - mu) * rs * g1.y + b1.y;
  y1.z = (x[6] - mu) * rs * g1.z + b1.z; y1.w = (x[7] - mu) * rs * g1.w + b1.w;
  float* p = out + (size_t)row * ND + lane * 8;
  *(float4*)p = y0;
  *(float4*)(p + 4) = y1;
}

extern "C" void kernel_launch(void* const* d_in, const int* in_sizes, int n_in,
                              void* d_out, int out_size, void* d_ws, size_t ws_size,
                              hipStream_t stream) {
  (void)in_sizes; (void)n_in; (void)out_size; (void)ws_size;
  const int*   adj   = (const int*)d_in[0];
  const float* hid   = (const float*)d_in[1];
  const float* W     = (const float*)d_in[2];
  const float* bias  = (const float*)d_in[3];
  const float* gamma = (const float*)d_in[4];
  const float* beta  = (const float*)d_in[5];
  float* out = (float*)d_out;

  char* ws = (char*)d_ws;
  unsigned short* WT     = (unsigned short*)ws;                 // 1 MiB
  unsigned short* Pt1    = (unsigned short*)(ws + 1048576);     // 16 MiB
  unsigned short* Pt2    = (unsigned short*)(ws + 17825792);    // 16 MiB
  unsigned*       packed = (unsigned*)(ws + 34603008);          // 4 MiB
  float*          invc   = (float*)(ws + 38797312);             // 128 KiB
  unsigned short* preS   = (unsigned short*)(ws + 38928384);    // 16 MiB (total ~53 MiB)

  k_wt  <<<dim3(16, 8), 256, 0, stream>>>(W, WT);
  k_pack<<<1024, 256, 0, stream>>>(adj, packed, invc);
  k_pre <<<512, 256, 0, stream>>>(hid, WT, Pt1, Pt2);
  k_main<<<512, 256, 0, stream>>>(packed, Pt1, Pt2, invc, bias, hid, preS);
  k_ln  <<<4096, 256, 0, stream>>>(preS, out, gamma, beta);
}

// Round 5
// 120.910 us; speedup vs baseline: 1.2171x; 1.2171x over previous
//
#include <hip/hip_runtime.h>

// B=16, N=1024, D=512, DIRECTIONS=2
#define NB 16
#define NN 1024
#define ND 512

typedef __attribute__((ext_vector_type(8))) short short8;   // 8 x bf16
typedef __attribute__((ext_vector_type(4))) float f32x4;

typedef const __attribute__((address_space(1))) void* gptr1;
typedef __attribute__((address_space(3))) void* lptr3;

#define VMCNT0() asm volatile("s_waitcnt vmcnt(0)" ::: "memory")
#define VMCNT8() asm volatile("s_waitcnt vmcnt(8)" ::: "memory")
#define LGKM0()  asm volatile("s_waitcnt lgkmcnt(0)" ::: "memory")
#define BAR()    __builtin_amdgcn_s_barrier()

union U8 { uint4 u; short8 s; };

static __device__ __forceinline__ unsigned f2bf(float f) {
  union { float f; unsigned u; } v; v.f = f;
  unsigned r = v.u + 0x7FFFu + ((v.u >> 16) & 1u);   // RNE
  return r >> 16;
}
static __device__ __forceinline__ float bf2f(unsigned short h) {
  union { unsigned u; float f; } v; v.u = ((unsigned)h) << 16;
  return v.f;
}

// ---------------- k_wt: W [1024][512] f32 -> WT [512][1024] bf16 -------------
__global__ void k_wt(const float* __restrict__ W, unsigned short* __restrict__ WT) {
  __shared__ float t[64][65];
  int r0 = blockIdx.x * 64;
  int c0 = blockIdx.y * 64;
  int tid = threadIdx.x;
#pragma unroll
  for (int i = 0; i < 4; ++i) {
    int f = i * 256 + tid;
    int r = f >> 4, cq = f & 15;
    float4 v = *(const float4*)(W + (size_t)(r0 + r) * ND + c0 + cq * 4);
    t[r][cq * 4 + 0] = v.x; t[r][cq * 4 + 1] = v.y;
    t[r][cq * 4 + 2] = v.z; t[r][cq * 4 + 3] = v.w;
  }
  __syncthreads();
#pragma unroll
  for (int i = 0; i < 8; ++i) {
    int f = i * 256 + tid;
    int oc = f >> 5;
    int on = (f & 31) * 2;
    unsigned lo = f2bf(t[on][oc]), hi = f2bf(t[on + 1][oc]);
    *(unsigned*)(WT + (size_t)(c0 + oc) * NN + r0 + on) = lo | (hi << 16);
  }
}

// -------- k_pack: adj int32 -> 2-bit codes (bit0: ==1, bit1: ==2) + counts ---
__global__ void k_pack(const int* __restrict__ adj, unsigned* __restrict__ packed,
                       float* __restrict__ invc) {
  int wid = threadIdx.x >> 6, lane = threadIdx.x & 63;
  int wrow0 = (blockIdx.x * 4 + wid) * 4;
#pragma unroll
  for (int r = 0; r < 4; ++r) {
    int row = wrow0 + r;
    const int* p = adj + (size_t)row * NN + lane * 16;
    unsigned u = 0;
#pragma unroll
    for (int i = 0; i < 4; ++i) {
      int4 v = *(const int4*)(p + i * 4);
      u |= ((unsigned)v.x << (8 * i)) | ((unsigned)v.y << (8 * i + 2))
         | ((unsigned)v.z << (8 * i + 4)) | ((unsigned)v.w << (8 * i + 6));
    }
    packed[(size_t)row * 64 + lane] = u;
    unsigned c1 = __popc(u & 0x55555555u);
    unsigned c2 = __popc(u & 0xAAAAAAAAu);
    unsigned pr = c1 | (c2 << 16);
#pragma unroll
    for (int o = 32; o; o >>= 1) pr += __shfl_xor(pr, o);
    if (lane == 0) {
      invc[row * 2 + 0] = 1.0f / ((float)(pr & 0xFFFFu) + 1e-13f);
      invc[row * 2 + 1] = 1.0f / ((float)(pr >> 16) + 1e-13f);
    }
  }
}

// -------- k_pre: Pt_j[b][d][m] = bf16( sum_c W[j*512+c][d] * hid[b][m][c] ) --
// A (WT) double-buffered via global_load_lds + counted vmcnt; B reg-stage+cast.
__global__ __launch_bounds__(256, 2) void k_pre(
    const float* __restrict__ hid, const unsigned short* __restrict__ WT,
    unsigned short* __restrict__ Pt1, unsigned short* __restrict__ Pt2) {
  __shared__ __align__(16) char smem[81920];   // A: 2 buf x 2 dir x 16KB; Bh: 16KB

  int phys = blockIdx.x;
  int logical = (phys & 7) * 64 + (phys >> 3);
  int b = logical >> 5;
  int rem = logical & 31;
  int dt = rem >> 3, mt = rem & 7;
  int d0 = dt * 128, m0 = mt * 128;

  int tid = threadIdx.x, lane = tid & 63, wid = tid >> 6;
  int wr = wid >> 1, wc = wid & 1;
  int srow = lane >> 3;
  int ssl = (lane & 7) ^ srow;

  const float* hb = hid + (size_t)b * NN * ND;
  char* Bh = smem + 65536;

  f32x4 acc1[4][4], acc2[4][4];
  f32x4 zero = {0.f, 0.f, 0.f, 0.f};
#pragma unroll
  for (int i = 0; i < 4; ++i)
#pragma unroll
    for (int j = 0; j < 4; ++j) { acc1[i][j] = zero; acc2[i][j] = zero; }

  float4 fc[8], fn[8];
#pragma unroll
  for (int it = 0; it < 8; ++it) {
    int f = it * 256 + tid;
    fc[it] = *(const float4*)(hb + (size_t)(m0 + (f >> 4)) * ND + (f & 15) * 4);
  }
  // A DMAs for kt=0 into buf0
#pragma unroll
  for (int i = 0; i < 4; ++i) {
    int q = wid * 4 + i;
    int r = q * 8 + srow;
    __builtin_amdgcn_global_load_lds((gptr1)(WT + (size_t)(d0 + r) * NN + ssl * 8),
                                     (lptr3)(smem + q * 1024), 16, 0, 0);
    __builtin_amdgcn_global_load_lds((gptr1)(WT + (size_t)(d0 + r) * NN + 512 + ssl * 8),
                                     (lptr3)(smem + 16384 + q * 1024), 16, 0, 0);
  }

#pragma unroll 1
  for (int kt = 0; kt < 8; ++kt) {
    int k0 = kt * 64;
    // 1. convert fc -> Bh (swizzled ds_write)
#pragma unroll
    for (int it = 0; it < 8; ++it) {
      int f = it * 256 + tid;
      int row = f >> 4, colq = f & 15;
      float4 v = fc[it];
      unsigned lo = f2bf(v.x) | (f2bf(v.y) << 16);
      unsigned hi = f2bf(v.z) | (f2bf(v.w) << 16);
      int addr = row * 128 + (((colq >> 1) ^ (row & 7)) * 16) + (colq & 1) * 8;
      *(uint2*)(Bh + addr) = make_uint2(lo, hi);
    }
    // 2. prefetch next hid panel
    if (kt < 7) {
#pragma unroll
      for (int it = 0; it < 8; ++it) {
        int f = it * 256 + tid;
        fn[it] = *(const float4*)(hb + (size_t)(m0 + (f >> 4)) * ND + k0 + 64 + (f & 15) * 4);
      }
    }
    // 3. A(kt) ready (keep fn + nothing else in flight beyond 8)
    if (kt == 7) { VMCNT0(); } else { VMCNT8(); }
    LGKM0();
    BAR();
    // 5. issue A(kt+1) into other buffer — flies across MFMA phase
    if (kt < 7) {
      char* ab = smem + (((kt + 1) & 1) << 15);
#pragma unroll
      for (int i = 0; i < 4; ++i) {
        int q = wid * 4 + i;
        int r = q * 8 + srow;
        __builtin_amdgcn_global_load_lds((gptr1)(WT + (size_t)(d0 + r) * NN + k0 + 64 + ssl * 8),
                                         (lptr3)(ab + q * 1024), 16, 0, 0);
        __builtin_amdgcn_global_load_lds((gptr1)(WT + (size_t)(d0 + r) * NN + 512 + k0 + 64 + ssl * 8),
                                         (lptr3)(ab + 16384 + q * 1024), 16, 0, 0);
      }
    }
    // 6. MFMA phase
    const char* ac = smem + ((kt & 1) << 15);
#pragma unroll
    for (int ks = 0; ks < 2; ++ks) {
      short8 a1[4], a2[4], bf[4];
#pragma unroll
      for (int mi = 0; mi < 4; ++mi) {
        int row = wr * 64 + mi * 16 + (lane & 15);
        int slot = (ks * 4 + (lane >> 4)) ^ (row & 7);
        a1[mi] = *(const short8*)(ac + row * 128 + slot * 16);
        a2[mi] = *(const short8*)(ac + 16384 + row * 128 + slot * 16);
      }
#pragma unroll
      for (int nj = 0; nj < 4; ++nj) {
        int col = wc * 64 + nj * 16 + (lane & 15);
        int slot = (ks * 4 + (lane >> 4)) ^ (col & 7);
        bf[nj] = *(const short8*)(Bh + col * 128 + slot * 16);
      }
#pragma unroll
      for (int mi = 0; mi < 4; ++mi)
#pragma unroll
        for (int nj = 0; nj < 4; ++nj) {
          acc1[mi][nj] = __builtin_amdgcn_mfma_f32_16x16x32_bf16(a1[mi], bf[nj], acc1[mi][nj], 0, 0, 0);
          acc2[mi][nj] = __builtin_amdgcn_mfma_f32_16x16x32_bf16(a2[mi], bf[nj], acc2[mi][nj], 0, 0, 0);
        }
    }
    // 7. all reads of Bh/abuf done before next overwrite
    BAR();
    if (kt < 7) {
#pragma unroll
      for (int it = 0; it < 8; ++it) fc[it] = fn[it];
    }
    __builtin_amdgcn_sched_barrier(0);
  }
  unsigned short* P1b = Pt1 + (size_t)b * ND * NN;
  unsigned short* P2b = Pt2 + (size_t)b * ND * NN;
#pragma unroll
  for (int mi = 0; mi < 4; ++mi) {
#pragma unroll
    for (int rr = 0; rr < 4; ++rr) {
      int rowd = d0 + wr * 64 + mi * 16 + (lane >> 4) * 4 + rr;
#pragma unroll
      for (int nj = 0; nj < 4; ++nj) {
        int colm = m0 + wc * 64 + nj * 16 + (lane & 15);
        P1b[(size_t)rowd * NN + colm] = (unsigned short)f2bf(acc1[mi][nj][rr]);
        P2b[(size_t)rowd * NN + colm] = (unsigned short)f2bf(acc2[mi][nj][rr]);
      }
    }
  }
}

// -------- k_main: preS[n][d] = bf16(relu(i1*(M1@Pt1) + i2*(M2@Pt2) + bias) + hid)
// Hybrid: A unpacked per-lane in registers from 2-bit codes (no LDS);
// B (Pt) double-buffered in LDS via global_load_lds + counted vmcnt(8).
__global__ __launch_bounds__(256, 2) void k_main(
    const unsigned* __restrict__ packed, const unsigned short* __restrict__ Pt1,
    const unsigned short* __restrict__ Pt2, const float* __restrict__ invc,
    const float* __restrict__ bias, const float* __restrict__ hid,
    unsigned short* __restrict__ preS) {
  __shared__ __align__(16) char smem[65536];   // [2 buf][2 dir][128][64] bf16

  int phys = blockIdx.x;
  int logical = (phys & 7) * 64 + (phys >> 3);
  int b = logical >> 5;
  int rem = logical & 31;
  int mt = rem >> 2, nt = rem & 3;
  int n0 = mt * 128, d0 = nt * 128;

  int tid = threadIdx.x, lane = tid & 63, wid = tid >> 6;
  int wr = wid >> 1, wc = wid & 1;
  int l15 = lane & 15, lq = lane >> 4;
  unsigned sh = (lq & 1) << 4;
  int srow = lane >> 3;
  int ssl = (lane & 7) ^ srow;

  // per-mi code pointers (word (lq>>1) of each kt's 4-word group)
  const unsigned* cp[4];
#pragma unroll
  for (int mi = 0; mi < 4; ++mi)
    cp[mi] = packed + ((size_t)b * NN + n0 + wr * 64 + mi * 16 + l15) * 64 + (lq >> 1);

  const unsigned short* pb1 = Pt1 + ((size_t)b * ND + d0) * NN;
  const unsigned short* pb2 = Pt2 + ((size_t)b * ND + d0) * NN;

  f32x4 acc1[4][4], acc2[4][4];
  f32x4 zero = {0.f, 0.f, 0.f, 0.f};
#pragma unroll
  for (int i = 0; i < 4; ++i)
#pragma unroll
    for (int j = 0; j < 4; ++j) { acc1[i][j] = zero; acc2[i][j] = zero; }

  unsigned cr[4][2], ncr[4][2];
#pragma unroll
  for (int mi = 0; mi < 4; ++mi) { cr[mi][0] = cp[mi][0]; cr[mi][1] = cp[mi][2]; }

  // stage B for kt=0 (buf0) and kt=1 (buf1)
#pragma unroll
  for (int i = 0; i < 4; ++i) {
    int q = wid * 4 + i;
    size_t ro = (size_t)(q * 8 + srow) * NN + ssl * 8;
    __builtin_amdgcn_global_load_lds((gptr1)(pb1 + ro), (lptr3)(smem + q * 1024), 16, 0, 0);
    __builtin_amdgcn_global_load_lds((gptr1)(pb2 + ro), (lptr3)(smem + 16384 + q * 1024), 16, 0, 0);
  }
#pragma unroll
  for (int i = 0; i < 4; ++i) {
    int q = wid * 4 + i;
    size_t ro = (size_t)(q * 8 + srow) * NN + 64 + ssl * 8;
    __builtin_amdgcn_global_load_lds((gptr1)(pb1 + ro), (lptr3)(smem + 32768 + q * 1024), 16, 0, 0);
    __builtin_amdgcn_global_load_lds((gptr1)(pb2 + ro), (lptr3)(smem + 49152 + q * 1024), 16, 0, 0);
  }

#pragma unroll 1
  for (int kt = 0; kt < 16; ++kt) {
    // A. buf[kt&1] ready; keep the 8 newest (next buffer's DMAs) in flight
    if (kt == 15) { VMCNT0(); } else { VMCNT8(); }
    BAR();
    // prefetch next codes (counted into next iter's vmcnt(8) drain)
    if (kt < 15) {
#pragma unroll
      for (int mi = 0; mi < 4; ++mi) { ncr[mi][0] = cp[mi][4]; ncr[mi][1] = cp[mi][6]; }
    }
    const char* bb = smem + ((kt & 1) << 15);
#pragma unroll
    for (int ks = 0; ks < 2; ++ks) {
      // ---- dir 1
      U8 a[4];
#pragma unroll
      for (int mi = 0; mi < 4; ++mi) {
        unsigned h = cr[mi][ks] >> sh;
#pragma unroll
        for (int j = 0; j < 4; ++j) {
          unsigned t = (h >> (4 * j)) & 5u;
          a[mi].u[j] = ((t | (t << 14)) & 0x00010001u) * 0x3F80u;
        }
      }
      short8 bfr[4];
#pragma unroll
      for (int nj = 0; nj < 4; ++nj) {
        int col = wc * 64 + nj * 16 + l15;
        int slot = (ks * 4 + lq) ^ (col & 7);
        bfr[nj] = *(const short8*)(bb + col * 128 + slot * 16);
      }
#pragma unroll
      for (int nj = 0; nj < 4; ++nj)
#pragma unroll
        for (int mi = 0; mi < 4; ++mi)
          acc1[mi][nj] = __builtin_amdgcn_mfma_f32_16x16x32_bf16(a[mi].s, bfr[nj], acc1[mi][nj], 0, 0, 0);
      // ---- dir 2
#pragma unroll
      for (int mi = 0; mi < 4; ++mi) {
        unsigned h = cr[mi][ks] >> sh;
#pragma unroll
        for (int j = 0; j < 4; ++j) {
          unsigned t = (h >> (4 * j + 1)) & 5u;
          a[mi].u[j] = ((t | (t << 14)) & 0x00010001u) * 0x3F80u;
        }
      }
#pragma unroll
      for (int nj = 0; nj < 4; ++nj) {
        int col = wc * 64 + nj * 16 + l15;
        int slot = (ks * 4 + lq) ^ (col & 7);
        bfr[nj] = *(const short8*)(bb + 16384 + col * 128 + slot * 16);
      }
#pragma unroll
      for (int nj = 0; nj < 4; ++nj)
#pragma unroll
        for (int mi = 0; mi < 4; ++mi)
          acc2[mi][nj] = __builtin_amdgcn_mfma_f32_16x16x32_bf16(a[mi].s, bfr[nj], acc2[mi][nj], 0, 0, 0);
    }
    // E. all waves done reading buf[kt&1]
    BAR();
    // F. restage buf[kt&1] with kt+2's panel
    if (kt < 14) {
      char* sb = (char*)smem + ((kt & 1) << 15);
      int k0n = kt * 64 + 128;
#pragma unroll
      for (int i = 0; i < 4; ++i) {
        int q = wid * 4 + i;
        size_t ro = (size_t)(q * 8 + srow) * NN + k0n + ssl * 8;
        __builtin_amdgcn_global_load_lds((gptr1)(pb1 + ro), (lptr3)(sb + q * 1024), 16, 0, 0);
        __builtin_amdgcn_global_load_lds((gptr1)(pb2 + ro), (lptr3)(sb + 16384 + q * 1024), 16, 0, 0);
      }
    }
    if (kt < 15) {
#pragma unroll
      for (int mi = 0; mi < 4; ++mi) {
        cr[mi][0] = ncr[mi][0]; cr[mi][1] = ncr[mi][1];
        cp[mi] += 4;
      }
    }
    __builtin_amdgcn_sched_barrier(0);
  }

  // ---- epilogue: combine dirs, bias, relu, residual; write pre-LN bf16
#pragma unroll
  for (int mi = 0; mi < 4; ++mi) {
#pragma unroll
    for (int rr = 0; rr < 4; ++rr) {
      int n = n0 + wr * 64 + mi * 16 + lq * 4 + rr;
      float i1 = invc[((size_t)b * NN + n) * 2 + 0];
      float i2 = invc[((size_t)b * NN + n) * 2 + 1];
      const float* hrow = hid + ((size_t)b * NN + n) * ND;
      unsigned short* prow = preS + ((size_t)b * NN + n) * ND;
#pragma unroll
      for (int nj = 0; nj < 4; ++nj) {
        int d = d0 + wc * 64 + nj * 16 + l15;
        float v = acc1[mi][nj][rr] * i1 + acc2[mi][nj][rr] * i2 + bias[d];
        v = fmaxf(v, 0.f);
        v += hrow[d];
        prow[d] = (unsigned short)f2bf(v);
      }
    }
  }
}

// ---------------- k_ln: rowwise LayerNorm, bf16 preS -> f32 out --------------
__global__ void k_ln(const unsigned short* __restrict__ preS, float* __restrict__ out,
                     const float* __restrict__ gamma, const float* __restrict__ beta) {
  int row = blockIdx.x * 4 + (threadIdx.x >> 6);
  int lane = threadIdx.x & 63;
  short8 raw = *(const short8*)(preS + (size_t)row * ND + lane * 8);
  float x[8];
#pragma unroll
  for (int i = 0; i < 8; ++i) x[i] = bf2f((unsigned short)raw[i]);
  float s = 0.f;
#pragma unroll
  for (int i = 0; i < 8; ++i) s += x[i];
#pragma unroll
  for (int o = 32; o; o >>= 1) s += __shfl_xor(s, o);
  float mu = s * (1.0f / 512.0f);
  float v = 0.f;
#pragma unroll
  for (int i = 0; i < 8; ++i) { float d = x[i] - mu; v += d * d; }
#pragma unroll
  for (int o = 32; o; o >>= 1) v += __shfl_xor(v, o);
  float rs = rsqrtf(v * (1.0f / 512.0f) + 1e-5f);
  float4 g0 = *(const float4*)(gamma + lane * 8);
  float4 g1 = *(const float4*)(gamma + lane * 8 + 4);
  float4 b0 = *(const float4*)(beta + lane * 8);
  float4 b1 = *(const float4*)(beta + lane * 8 + 4);
  float4 y0, y1;
  y0.x = (x[0] - mu) * rs * g0.x + b0.x; y0.y = (x[1] - mu) * rs * g0.y + b0.y;
  y0.z = (x[2] - mu) * rs * g0.z + b0.z; y0.w = (x[3] - mu) * rs * g0.w + b0.w;
  y1.x = (x[4] - mu) * rs * g1.x + b1.x; y1.y = (x[5] - mu) * rs * g1.y + b1.y;
  y1.z = (x[6] - mu) * rs * g1.z + b1.z; y1.w = (x[7] - mu) * rs * g1.w + b1.w;
  float* p = out + (size_t)row * ND + lane * 8;
  *(float4*)p = y0;
  *(float4*)(p + 4) = y1;
}

extern "C" void kernel_launch(void* const* d_in, const int* in_sizes, int n_in,
                              void* d_out, int out_size, void* d_ws, size_t ws_size,
                              hipStream_t stream) {
  (void)in_sizes; (void)n_in; (void)out_size; (void)ws_size;
  const int*   adj   = (const int*)d_in[0];
  const float* hid   = (const float*)d_in[1];
  const float* W     = (const float*)d_in[2];
  const float* bias  = (const float*)d_in[3];
  const float* gamma = (const float*)d_in[4];
  const float* beta  = (const float*)d_in[5];
  float* out = (float*)d_out;

  char* ws = (char*)d_ws;
  unsigned short* WT     = (unsigned short*)ws;                 // 1 MiB
  unsigned short* Pt1    = (unsigned short*)(ws + 1048576);     // 16 MiB
  unsigned short* Pt2    = (unsigned short*)(ws + 17825792);    // 16 MiB
  unsigned*       packed = (unsigned*)(ws + 34603008);          // 4 MiB
  float*          invc   = (float*)(ws + 38797312);             // 128 KiB
  unsigned short* preS   = (unsigned short*)(ws + 38928384);    // 16 MiB

  k_wt  <<<dim3(16, 8), 256, 0, stream>>>(W, WT);
  k_pack<<<1024, 256, 0, stream>>>(adj, packed, invc);
  k_pre <<<512, 256, 0, stream>>>(hid, WT, Pt1, Pt2);
  k_main<<<512, 256, 0, stream>>>(packed, Pt1, Pt2, invc, bias, hid, preS);
  k_ln  <<<4096, 256, 0, stream>>>(preS, out, gamma, beta);
}

// Round 6
// 111.572 us; speedup vs baseline: 1.3190x; 1.0837x over previous
//
#include <hip/hip_runtime.h>

// B=16, N=1024, D=512, DIRECTIONS=2
#define NB 16
#define NN 1024
#define ND 512

typedef __attribute__((ext_vector_type(8))) short short8;   // 8 x bf16
typedef __attribute__((ext_vector_type(4))) float f32x4;

typedef const __attribute__((address_space(1))) void* gptr1;
typedef __attribute__((address_space(3))) void* lptr3;

#define VMCNT0() asm volatile("s_waitcnt vmcnt(0)" ::: "memory")
#define VMCNT8() asm volatile("s_waitcnt vmcnt(8)" ::: "memory")
#define LGKM0()  asm volatile("s_waitcnt lgkmcnt(0)" ::: "memory")
#define BAR()    __builtin_amdgcn_s_barrier()

static __device__ __forceinline__ unsigned f2bf(float f) {
  union { float f; unsigned u; } v; v.f = f;
  unsigned r = v.u + 0x7FFFu + ((v.u >> 16) & 1u);   // RNE
  return r >> 16;
}
static __device__ __forceinline__ float bf2f(unsigned short h) {
  union { unsigned u; float f; } v; v.u = ((unsigned)h) << 16;
  return v.f;
}
// 2-bit codes -> packed pair of bf16 {0,1}: bits (sh) and (sh+2) of w
static __device__ __forceinline__ unsigned mk2(unsigned w, int sh) {
  unsigned t = (w >> sh) & 5u;
  return ((t | (t << 14)) & 0x00010001u) * 0x3F80u;
}

// ---------------- k_wt: W [1024][512] f32 -> WT [512][1024] bf16 -------------
__global__ void k_wt(const float* __restrict__ W, unsigned short* __restrict__ WT) {
  __shared__ float t[64][65];
  int r0 = blockIdx.x * 64;
  int c0 = blockIdx.y * 64;
  int tid = threadIdx.x;
#pragma unroll
  for (int i = 0; i < 4; ++i) {
    int f = i * 256 + tid;
    int r = f >> 4, cq = f & 15;
    float4 v = *(const float4*)(W + (size_t)(r0 + r) * ND + c0 + cq * 4);
    t[r][cq * 4 + 0] = v.x; t[r][cq * 4 + 1] = v.y;
    t[r][cq * 4 + 2] = v.z; t[r][cq * 4 + 3] = v.w;
  }
  __syncthreads();
#pragma unroll
  for (int i = 0; i < 8; ++i) {
    int f = i * 256 + tid;
    int oc = f >> 5;
    int on = (f & 31) * 2;
    unsigned lo = f2bf(t[on][oc]), hi = f2bf(t[on + 1][oc]);
    *(unsigned*)(WT + (size_t)(c0 + oc) * NN + r0 + on) = lo | (hi << 16);
  }
}

// -------- k_pack: adj int32 -> 2-bit codes (bit0: ==1, bit1: ==2) + counts ---
__global__ void k_pack(const int* __restrict__ adj, unsigned* __restrict__ packed,
                       float* __restrict__ invc) {
  int wid = threadIdx.x >> 6, lane = threadIdx.x & 63;
  int wrow0 = (blockIdx.x * 4 + wid) * 4;
#pragma unroll
  for (int r = 0; r < 4; ++r) {
    int row = wrow0 + r;
    const int* p = adj + (size_t)row * NN + lane * 16;
    unsigned u = 0;
#pragma unroll
    for (int i = 0; i < 4; ++i) {
      int4 v = *(const int4*)(p + i * 4);
      u |= ((unsigned)v.x << (8 * i)) | ((unsigned)v.y << (8 * i + 2))
         | ((unsigned)v.z << (8 * i + 4)) | ((unsigned)v.w << (8 * i + 6));
    }
    packed[(size_t)row * 64 + lane] = u;
    unsigned c1 = __popc(u & 0x55555555u);
    unsigned c2 = __popc(u & 0xAAAAAAAAu);
    unsigned pr = c1 | (c2 << 16);
#pragma unroll
    for (int o = 32; o; o >>= 1) pr += __shfl_xor(pr, o);
    if (lane == 0) {
      invc[row * 2 + 0] = 1.0f / ((float)(pr & 0xFFFFu) + 1e-13f);
      invc[row * 2 + 1] = 1.0f / ((float)(pr >> 16) + 1e-13f);
    }
  }
}

// -------- k_pre: Pt_j[b][d][m] = bf16( sum_c W[j*512+c][d] * hid[b][m][c] ) --
// (unchanged from R5: A dbuf via global_load_lds + counted vmcnt; B reg+cast)
__global__ __launch_bounds__(256, 2) void k_pre(
    const float* __restrict__ hid, const unsigned short* __restrict__ WT,
    unsigned short* __restrict__ Pt1, unsigned short* __restrict__ Pt2) {
  __shared__ __align__(16) char smem[81920];

  int phys = blockIdx.x;
  int logical = (phys & 7) * 64 + (phys >> 3);
  int b = logical >> 5;
  int rem = logical & 31;
  int dt = rem >> 3, mt = rem & 7;
  int d0 = dt * 128, m0 = mt * 128;

  int tid = threadIdx.x, lane = tid & 63, wid = tid >> 6;
  int wr = wid >> 1, wc = wid & 1;
  int srow = lane >> 3;
  int ssl = (lane & 7) ^ srow;

  const float* hb = hid + (size_t)b * NN * ND;
  char* Bh = smem + 65536;

  f32x4 acc1[4][4], acc2[4][4];
  f32x4 zero = {0.f, 0.f, 0.f, 0.f};
#pragma unroll
  for (int i = 0; i < 4; ++i)
#pragma unroll
    for (int j = 0; j < 4; ++j) { acc1[i][j] = zero; acc2[i][j] = zero; }

  float4 fc[8], fn[8];
#pragma unroll
  for (int it = 0; it < 8; ++it) {
    int f = it * 256 + tid;
    fc[it] = *(const float4*)(hb + (size_t)(m0 + (f >> 4)) * ND + (f & 15) * 4);
  }
#pragma unroll
  for (int i = 0; i < 4; ++i) {
    int q = wid * 4 + i;
    int r = q * 8 + srow;
    __builtin_amdgcn_global_load_lds((gptr1)(WT + (size_t)(d0 + r) * NN + ssl * 8),
                                     (lptr3)(smem + q * 1024), 16, 0, 0);
    __builtin_amdgcn_global_load_lds((gptr1)(WT + (size_t)(d0 + r) * NN + 512 + ssl * 8),
                                     (lptr3)(smem + 16384 + q * 1024), 16, 0, 0);
  }

#pragma unroll 1
  for (int kt = 0; kt < 8; ++kt) {
    int k0 = kt * 64;
#pragma unroll
    for (int it = 0; it < 8; ++it) {
      int f = it * 256 + tid;
      int row = f >> 4, colq = f & 15;
      float4 v = fc[it];
      unsigned lo = f2bf(v.x) | (f2bf(v.y) << 16);
      unsigned hi = f2bf(v.z) | (f2bf(v.w) << 16);
      int addr = row * 128 + (((colq >> 1) ^ (row & 7)) * 16) + (colq & 1) * 8;
      *(uint2*)(Bh + addr) = make_uint2(lo, hi);
    }
    if (kt < 7) {
#pragma unroll
      for (int it = 0; it < 8; ++it) {
        int f = it * 256 + tid;
        fn[it] = *(const float4*)(hb + (size_t)(m0 + (f >> 4)) * ND + k0 + 64 + (f & 15) * 4);
      }
    }
    if (kt == 7) { VMCNT0(); } else { VMCNT8(); }
    LGKM0();
    BAR();
    if (kt < 7) {
      char* ab = smem + (((kt + 1) & 1) << 15);
#pragma unroll
      for (int i = 0; i < 4; ++i) {
        int q = wid * 4 + i;
        int r = q * 8 + srow;
        __builtin_amdgcn_global_load_lds((gptr1)(WT + (size_t)(d0 + r) * NN + k0 + 64 + ssl * 8),
                                         (lptr3)(ab + q * 1024), 16, 0, 0);
        __builtin_amdgcn_global_load_lds((gptr1)(WT + (size_t)(d0 + r) * NN + 512 + k0 + 64 + ssl * 8),
                                         (lptr3)(ab + 16384 + q * 1024), 16, 0, 0);
      }
    }
    const char* ac = smem + ((kt & 1) << 15);
#pragma unroll
    for (int ks = 0; ks < 2; ++ks) {
      short8 a1[4], a2[4], bf[4];
#pragma unroll
      for (int mi = 0; mi < 4; ++mi) {
        int row = wr * 64 + mi * 16 + (lane & 15);
        int slot = (ks * 4 + (lane >> 4)) ^ (row & 7);
        a1[mi] = *(const short8*)(ac + row * 128 + slot * 16);
        a2[mi] = *(const short8*)(ac + 16384 + row * 128 + slot * 16);
      }
#pragma unroll
      for (int nj = 0; nj < 4; ++nj) {
        int col = wc * 64 + nj * 16 + (lane & 15);
        int slot = (ks * 4 + (lane >> 4)) ^ (col & 7);
        bf[nj] = *(const short8*)(Bh + col * 128 + slot * 16);
      }
#pragma unroll
      for (int mi = 0; mi < 4; ++mi)
#pragma unroll
        for (int nj = 0; nj < 4; ++nj) {
          acc1[mi][nj] = __builtin_amdgcn_mfma_f32_16x16x32_bf16(a1[mi], bf[nj], acc1[mi][nj], 0, 0, 0);
          acc2[mi][nj] = __builtin_amdgcn_mfma_f32_16x16x32_bf16(a2[mi], bf[nj], acc2[mi][nj], 0, 0, 0);
        }
    }
    BAR();
    if (kt < 7) {
#pragma unroll
      for (int it = 0; it < 8; ++it) fc[it] = fn[it];
    }
    __builtin_amdgcn_sched_barrier(0);
  }
  unsigned short* P1b = Pt1 + (size_t)b * ND * NN;
  unsigned short* P2b = Pt2 + (size_t)b * ND * NN;
#pragma unroll
  for (int mi = 0; mi < 4; ++mi) {
#pragma unroll
    for (int rr = 0; rr < 4; ++rr) {
      int rowd = d0 + wr * 64 + mi * 16 + (lane >> 4) * 4 + rr;
#pragma unroll
      for (int nj = 0; nj < 4; ++nj) {
        int colm = m0 + wc * 64 + nj * 16 + (lane & 15);
        P1b[(size_t)rowd * NN + colm] = (unsigned short)f2bf(acc1[mi][nj][rr]);
        P2b[(size_t)rowd * NN + colm] = (unsigned short)f2bf(acc2[mi][nj][rr]);
      }
    }
  }
}

// -------- k_main: preS[n][d] = bf16(relu(i1*(M1@Pt1) + i2*(M2@Pt2) + bias) + hid)
// BK=32, EVERYTHING double-buffered, ONE barrier per K-step:
//   A (masks): shared LDS conversion from 2-bit codes, written to buf nxt
//   B (Pt):    global_load_lds DMA into buf nxt, issued at top of kt
//   MFMAs on buf cur live in the same barrier-free region as the staging.
// LDS [64KB]: A [buf][dir][128][32]bf16 @0, B same @32768. 2 blocks/CU.
__global__ __launch_bounds__(256, 2) void k_main(
    const unsigned* __restrict__ packed, const unsigned short* __restrict__ Pt1,
    const unsigned short* __restrict__ Pt2, const float* __restrict__ invc,
    const float* __restrict__ bias, const float* __restrict__ hid,
    unsigned short* __restrict__ preS) {
  __shared__ __align__(16) char smem[65536];
  char* smA = smem;
  char* smB = smem + 32768;

  int phys = blockIdx.x;
  int logical = (phys & 7) * 64 + (phys >> 3);
  int b = logical >> 5;
  int rem = logical & 31;
  int mt = rem >> 2, nt = rem & 3;
  int n0 = mt * 128, d0 = nt * 128;

  int tid = threadIdx.x, lane = tid & 63, wid = tid >> 6;
  int wr = wid >> 1, wc = wid & 1;
  int l15 = lane & 15, lq = lane >> 4;
  int rowown = tid >> 1, h = tid & 1;   // conversion ownership: 16 elems

  const unsigned* cpp = packed + ((size_t)b * NN + n0 + rowown) * 64 + h;
  const unsigned short* pb1 = Pt1 + ((size_t)b * ND + d0) * NN;
  const unsigned short* pb2 = Pt2 + ((size_t)b * ND + d0) * NN;

  int srow = lane >> 2;          // DMA: 16 rows per 1KB call
  int scol = (lane & 3) * 8;     // 4 x 16B per row

  f32x4 acc1[4][4], acc2[4][4];
  f32x4 zero = {0.f, 0.f, 0.f, 0.f};
#pragma unroll
  for (int i = 0; i < 4; ++i)
#pragma unroll
    for (int j = 0; j < 4; ++j) { acc1[i][j] = zero; acc2[i][j] = zero; }

  // ---- prologue: stage kt=0 into buf0
  unsigned c_cur = cpp[0];
#pragma unroll
  for (int i = 0; i < 2; ++i) {
    int q = wid * 2 + i;
    size_t ro = (size_t)(q * 16 + srow) * NN + scol;
    __builtin_amdgcn_global_load_lds((gptr1)(pb1 + ro), (lptr3)(smB + q * 1024), 16, 0, 0);
    __builtin_amdgcn_global_load_lds((gptr1)(pb2 + ro), (lptr3)(smB + 8192 + q * 1024), 16, 0, 0);
  }
  {
    char* wp = smA + rowown * 64 + h * 32;
    uint4 x0, x1, y0, y1;
    x0.x = mk2(c_cur, 0);  x0.y = mk2(c_cur, 4);  x0.z = mk2(c_cur, 8);  x0.w = mk2(c_cur, 12);
    x1.x = mk2(c_cur, 16); x1.y = mk2(c_cur, 20); x1.z = mk2(c_cur, 24); x1.w = mk2(c_cur, 28);
    y0.x = mk2(c_cur, 1);  y0.y = mk2(c_cur, 5);  y0.z = mk2(c_cur, 9);  y0.w = mk2(c_cur, 13);
    y1.x = mk2(c_cur, 17); y1.y = mk2(c_cur, 21); y1.z = mk2(c_cur, 25); y1.w = mk2(c_cur, 29);
    *(uint4*)wp = x0; *(uint4*)(wp + 16) = x1;
    *(uint4*)(wp + 8192) = y0; *(uint4*)(wp + 8192 + 16) = y1;
  }
  unsigned c_nxt = cpp[2];
  LGKM0(); VMCNT0(); BAR();

#pragma unroll 1
  for (int kt = 0; kt < 32; ++kt) {
    int cb = (kt & 1) << 14;
    int nb = cb ^ 16384;
    // issue B[kt+1] DMAs first — in flight across the whole K-step
    if (kt < 31) {
      int k0n = (kt + 1) * 32;
#pragma unroll
      for (int i = 0; i < 2; ++i) {
        int q = wid * 2 + i;
        size_t ro = (size_t)(q * 16 + srow) * NN + k0n + scol;
        __builtin_amdgcn_global_load_lds((gptr1)(pb1 + ro), (lptr3)(smB + nb + q * 1024), 16, 0, 0);
        __builtin_amdgcn_global_load_lds((gptr1)(pb2 + ro), (lptr3)(smB + nb + 8192 + q * 1024), 16, 0, 0);
      }
    }
    // fragment reads from buf cur (natural layout is b128-conflict-free at 64B rows)
    short8 a1[4], a2[4], b1f[4], b2f[4];
#pragma unroll
    for (int mi = 0; mi < 4; ++mi) {
      int r = wr * 64 + mi * 16 + l15;
      a1[mi] = *(const short8*)(smA + cb + r * 64 + lq * 16);
      a2[mi] = *(const short8*)(smA + cb + 8192 + r * 64 + lq * 16);
    }
#pragma unroll
    for (int nj = 0; nj < 4; ++nj) {
      int c = wc * 64 + nj * 16 + l15;
      b1f[nj] = *(const short8*)(smB + cb + c * 64 + lq * 16);
      b2f[nj] = *(const short8*)(smB + cb + 8192 + c * 64 + lq * 16);
    }
    // convert codes(kt+1) -> A[nxt]; overlaps with MFMAs below (no barrier between)
    if (kt < 31) {
      char* wp = smA + nb + rowown * 64 + h * 32;
      uint4 x0, x1, y0, y1;
      x0.x = mk2(c_nxt, 0);  x0.y = mk2(c_nxt, 4);  x0.z = mk2(c_nxt, 8);  x0.w = mk2(c_nxt, 12);
      x1.x = mk2(c_nxt, 16); x1.y = mk2(c_nxt, 20); x1.z = mk2(c_nxt, 24); x1.w = mk2(c_nxt, 28);
      y0.x = mk2(c_nxt, 1);  y0.y = mk2(c_nxt, 5);  y0.z = mk2(c_nxt, 9);  y0.w = mk2(c_nxt, 13);
      y1.x = mk2(c_nxt, 17); y1.y = mk2(c_nxt, 21); y1.z = mk2(c_nxt, 25); y1.w = mk2(c_nxt, 29);
      *(uint4*)wp = x0; *(uint4*)(wp + 16) = x1;
      *(uint4*)(wp + 8192) = y0; *(uint4*)(wp + 8192 + 16) = y1;
      if (kt < 30) c_nxt = cpp[(kt + 2) * 2];
    }
    // 32 MFMAs on buf cur
#pragma unroll
    for (int nj = 0; nj < 4; ++nj)
#pragma unroll
      for (int mi = 0; mi < 4; ++mi)
        acc1[mi][nj] = __builtin_amdgcn_mfma_f32_16x16x32_bf16(a1[mi], b1f[nj], acc1[mi][nj], 0, 0, 0);
#pragma unroll
    for (int nj = 0; nj < 4; ++nj)
#pragma unroll
      for (int mi = 0; mi < 4; ++mi)
        acc2[mi][nj] = __builtin_amdgcn_mfma_f32_16x16x32_bf16(a2[mi], b2f[nj], acc2[mi][nj], 0, 0, 0);
    // single publish point: A-writes visible, B-DMAs landed, then swap
    LGKM0(); VMCNT0(); BAR();
    __builtin_amdgcn_sched_barrier(0);
  }

  // ---- epilogue: combine dirs, bias, relu, residual; write pre-LN bf16
#pragma unroll
  for (int mi = 0; mi < 4; ++mi) {
#pragma unroll
    for (int rr = 0; rr < 4; ++rr) {
      int n = n0 + wr * 64 + mi * 16 + lq * 4 + rr;
      float i1 = invc[((size_t)b * NN + n) * 2 + 0];
      float i2 = invc[((size_t)b * NN + n) * 2 + 1];
      const float* hrow = hid + ((size_t)b * NN + n) * ND;
      unsigned short* prow = preS + ((size_t)b * NN + n) * ND;
#pragma unroll
      for (int nj = 0; nj < 4; ++nj) {
        int d = d0 + wc * 64 + nj * 16 + l15;
        float v = acc1[mi][nj][rr] * i1 + acc2[mi][nj][rr] * i2 + bias[d];
        v = fmaxf(v, 0.f);
        v += hrow[d];
        prow[d] = (unsigned short)f2bf(v);
      }
    }
  }
}

// ---------------- k_ln: rowwise LayerNorm, bf16 preS -> f32 out --------------
__global__ void k_ln(const unsigned short* __restrict__ preS, float* __restrict__ out,
                     const float* __restrict__ gamma, const float* __restrict__ beta) {
  int row = blockIdx.x * 4 + (threadIdx.x >> 6);
  int lane = threadIdx.x & 63;
  short8 raw = *(const short8*)(preS + (size_t)row * ND + lane * 8);
  float x[8];
#pragma unroll
  for (int i = 0; i < 8; ++i) x[i] = bf2f((unsigned short)raw[i]);
  float s = 0.f;
#pragma unroll
  for (int i = 0; i < 8; ++i) s += x[i];
#pragma unroll
  for (int o = 32; o; o >>= 1) s += __shfl_xor(s, o);
  float mu = s * (1.0f / 512.0f);
  float v = 0.f;
#pragma unroll
  for (int i = 0; i < 8; ++i) { float d = x[i] - mu; v += d * d; }
#pragma unroll
  for (int o = 32; o; o >>= 1) v += __shfl_xor(v, o);
  float rs = rsqrtf(v * (1.0f / 512.0f) + 1e-5f);
  float4 g0 = *(const float4*)(gamma + lane * 8);
  float4 g1 = *(const float4*)(gamma + lane * 8 + 4);
  float4 b0 = *(const float4*)(beta + lane * 8);
  float4 b1 = *(const float4*)(beta + lane * 8 + 4);
  float4 y0, y1;
  y0.x = (x[0] - mu) * rs * g0.x + b0.x; y0.y = (x[1] - mu) * rs * g0.y + b0.y;
  y0.z = (x[2] - mu) * rs * g0.z + b0.z; y0.w = (x[3] - mu) * rs * g0.w + b0.w;
  y1.x = (x[4] - mu) * rs * g1.x + b1.x; y1.y = (x[5] - mu) * rs * g1.y + b1.y;
  y1.z = (x[6] - mu) * rs * g1.z + b1.z; y1.w = (x[7] - mu) * rs * g1.w + b1.w;
  float* p = out + (size_t)row * ND + lane * 8;
  *(float4*)p = y0;
  *(float4*)(p + 4) = y1;
}

extern "C" void kernel_launch(void* const* d_in, const int* in_sizes, int n_in,
                              void* d_out, int out_size, void* d_ws, size_t ws_size,
                              hipStream_t stream) {
  (void)in_sizes; (void)n_in; (void)out_size; (void)ws_size;
  const int*   adj   = (const int*)d_in[0];
  const float* hid   = (const float*)d_in[1];
  const float* W     = (const float*)d_in[2];
  const float* bias  = (const float*)d_in[3];
  const float* gamma = (const float*)d_in[4];
  const float* beta  = (const float*)d_in[5];
  float* out = (float*)d_out;

  char* ws = (char*)d_ws;
  unsigned short* WT     = (unsigned short*)ws;                 // 1 MiB
  unsigned short* Pt1    = (unsigned short*)(ws + 1048576);     // 16 MiB
  unsigned short* Pt2    = (unsigned short*)(ws + 17825792);    // 16 MiB
  unsigned*       packed = (unsigned*)(ws + 34603008);          // 4 MiB
  float*          invc   = (float*)(ws + 38797312);             // 128 KiB
  unsigned short* preS   = (unsigned short*)(ws + 38928384);    // 16 MiB

  k_wt  <<<dim3(16, 8), 256, 0, stream>>>(W, WT);
  k_pack<<<1024, 256, 0, stream>>>(adj, packed, invc);
  k_pre <<<512, 256, 0, stream>>>(hid, WT, Pt1, Pt2);
  k_main<<<512, 256, 0, stream>>>(packed, Pt1, Pt2, invc, bias, hid, preS);
  k_ln  <<<4096, 256, 0, stream>>>(preS, out, gamma, beta);
}